// Round 1
// baseline (1370.523 us; speedup 1.0000x reference)
//
#include <hip/hip_runtime.h>

// Problem constants (match reference setup_inputs)
constexpr int B = 64, T = 256, M = 16, A = 32, H = 64;
constexpr int NCOL = M * H + H * H + H;  // 1024 + 4096 + 64 = 5184
constexpr int NG = NCOL / H;             // 81 groups of 64 cols

// ---------------------------------------------------------------------------
// Gate kernel: for a time-chunk, compute G[b*chunk+tc][5184] =
//   [ softmax rows of J (16 groups) | softmax rows of R (64 groups) | sigmoid Og (1 group) ]
// One 64-thread block handles 64 (b,t)-rows x one 64-col group.
// Per-thread: its row's x_a in 32 regs; group's W rows broadcast from LDS;
// 64 accumulators in regs -> softmax is thread-local.
// ---------------------------------------------------------------------------
__global__ __launch_bounds__(64) void gate_kernel(
    const float* __restrict__ x_a,
    const float* __restrict__ Wj, const float* __restrict__ bj,
    const float* __restrict__ Wr, const float* __restrict__ br,
    const float* __restrict__ Wo, const float* __restrict__ bo,
    float* __restrict__ G, int t0, int chunk)
{
    const int g = blockIdx.x;
    const int l = threadIdx.x;
    const int r = blockIdx.y * 64 + l;        // row within chunk: r = b*chunk + tc
    const int b = r / chunk, tc = r % chunk;

    __shared__ float Wlds[64][32];
    __shared__ float blds[64];

    const float* W; const float* bias; int row0;
    if (g < 16)      { W = Wj; bias = bj; row0 = g * H; }
    else if (g < 80) { W = Wr; bias = br; row0 = (g - 16) * H; }
    else             { W = Wo; bias = bo; row0 = 0; }

    {   // stage this group's 64 W-rows (64x32 f32 = 8 KB) + bias
        const float4* src = (const float4*)(W + (size_t)(row0 + l) * A);
        float4* dst = (float4*)&Wlds[l][0];
        #pragma unroll
        for (int j = 0; j < 8; ++j) dst[j] = src[j];
        blds[l] = bias[row0 + l];
    }

    float xa[32];
    {
        const float4* src = (const float4*)(x_a + ((size_t)b * T + t0 + tc) * A);
        #pragma unroll
        for (int j = 0; j < 8; ++j) {
            float4 v = src[j];
            xa[4*j] = v.x; xa[4*j+1] = v.y; xa[4*j+2] = v.z; xa[4*j+3] = v.w;
        }
    }
    __syncthreads();

    float acc[64];
    #pragma unroll
    for (int c = 0; c < 64; ++c) {
        const float4* w = (const float4*)&Wlds[c][0];  // wave-uniform -> LDS broadcast
        float s = 0.f;
        #pragma unroll
        for (int j = 0; j < 8; ++j) {
            float4 wv = w[j];
            s += xa[4*j] * wv.x + xa[4*j+1] * wv.y + xa[4*j+2] * wv.z + xa[4*j+3] * wv.w;
        }
        acc[c] = s + blds[c];
    }

    if (g < 80) {  // softmax over the 64 cols (thread-local)
        float mx = acc[0];
        #pragma unroll
        for (int c = 1; c < 64; ++c) mx = fmaxf(mx, acc[c]);
        float sum = 0.f;
        #pragma unroll
        for (int c = 0; c < 64; ++c) { acc[c] = __expf(acc[c] - mx); sum += acc[c]; }
        float inv = 1.f / sum;
        #pragma unroll
        for (int c = 0; c < 64; ++c) acc[c] *= inv;
    } else {       // out-gate sigmoid
        #pragma unroll
        for (int c = 0; c < 64; ++c) acc[c] = 1.f / (1.f + __expf(-acc[c]));
    }

    float4* outp = (float4*)(G + (size_t)r * NCOL + g * H);
    #pragma unroll
    for (int j = 0; j < 16; ++j)
        outp[j] = make_float4(acc[4*j], acc[4*j+1], acc[4*j+2], acc[4*j+3]);
}

// ---------------------------------------------------------------------------
// Scan kernel: one block per batch, serial over the chunk's timesteps.
// m_new[k] = sum_m x_m[m]*J[m][k] + sum_h c[h]*R[h][k];
// c_new = (1-o)*m_new written to out; pred fused at t==T-1.
// Carry between chunk launches is re-read from the c output region.
// ---------------------------------------------------------------------------
__global__ __launch_bounds__(256) void scan_kernel(
    const float* __restrict__ G,
    const float* __restrict__ x_m,
    const float* __restrict__ Wfc, const float* __restrict__ bfc,
    float* __restrict__ out, int t0, int chunk, int first)
{
    const int b = blockIdx.x;
    const int tid = threadIdx.x;
    const int q = tid >> 6, k = tid & 63;

    __shared__ float c_sh[64];
    __shared__ float part[4][64];

    float* cbase = out + B;  // c region: cbase[(b*T + t)*H + k]
    if (tid < 64)
        c_sh[tid] = first ? 0.f : cbase[((size_t)b * T + (t0 - 1)) * H + tid];
    __syncthreads();

    for (int tc = 0; tc < chunk; ++tc) {
        const int t = t0 + tc;
        const float* row = G + (size_t)(b * chunk + tc) * NCOL;

        float p = 0.f;
        #pragma unroll
        for (int i = 0; i < 4; ++i) {        // J contribution (m = q*4 .. q*4+3)
            int m = q * 4 + i;
            float xm = x_m[((size_t)b * T + t) * M + m];   // wave-uniform
            p += xm * row[m * H + k];                      // coalesced 256B row
        }
        #pragma unroll
        for (int i = 0; i < 16; ++i) {       // R contribution (h = q*16 .. +15)
            int h = q * 16 + i;
            p += c_sh[h] * row[M * H + h * H + k];
        }
        part[q][k] = p;
        __syncthreads();

        if (q == 0) {
            float m_new = part[0][k] + part[1][k] + part[2][k] + part[3][k];
            float o = row[M * H + H * H + k];
            float c_new = (1.f - o) * m_new;
            cbase[((size_t)b * T + t) * H + k] = c_new;
            c_sh[k] = c_new;
            if (t == T - 1) {
                float v = o * m_new * Wfc[k];
                #pragma unroll
                for (int off = 32; off > 0; off >>= 1) v += __shfl_down(v, off);
                if (k == 0) out[b] = v + bfc[0];
            }
        }
        __syncthreads();
    }
}

// ---------------------------------------------------------------------------
extern "C" void kernel_launch(void* const* d_in, const int* in_sizes, int n_in,
                              void* d_out, int out_size, void* d_ws, size_t ws_size,
                              hipStream_t stream) {
    const float* x_m = (const float*)d_in[0];
    const float* x_a = (const float*)d_in[1];
    const float* Wj  = (const float*)d_in[2];
    const float* bj  = (const float*)d_in[3];
    const float* Wr  = (const float*)d_in[4];
    const float* br  = (const float*)d_in[5];
    const float* Wo  = (const float*)d_in[6];
    const float* bo  = (const float*)d_in[7];
    const float* Wfc = (const float*)d_in[8];
    const float* bfc = (const float*)d_in[9];
    float* out = (float*)d_out;
    float* G   = (float*)d_ws;

    // time-chunk sized to the workspace (42.5 MB at chunk=32)
    int chunk = 32;
    while (chunk > 1 && (size_t)B * chunk * NCOL * sizeof(float) > ws_size) chunk >>= 1;

    for (int t0 = 0; t0 < T; t0 += chunk) {
        gate_kernel<<<dim3(NG, (B * chunk) / 64), 64, 0, stream>>>(
            x_a, Wj, bj, Wr, br, Wo, bo, G, t0, chunk);
        scan_kernel<<<64, 256, 0, stream>>>(
            G, x_m, Wfc, bfc, out, t0, chunk, t0 == 0 ? 1 : 0);
    }
}

// Round 2
// 640.896 us; speedup vs baseline: 2.1384x; 2.1384x over previous
//
#include <hip/hip_runtime.h>

// Problem constants (match reference setup_inputs)
constexpr int B = 64, T = 256, M = 16, A = 32, H = 64;
constexpr int NCOL = M * H + H * H + H;  // 1024 + 4096 + 64 = 5184
constexpr int NG = NCOL / H;             // 81 groups of 64 cols

// ---------------------------------------------------------------------------
// Gate kernel v2: 256 threads/block, each thread computes TWO rows of one
// 64-col group (W staged once in LDS, broadcast-read, amortized over 2 rows).
// grid = (81 groups, ceil(rows/512)).
// ---------------------------------------------------------------------------
__global__ __launch_bounds__(256) void gate_kernel(
    const float* __restrict__ x_a,
    const float* __restrict__ Wj, const float* __restrict__ bj,
    const float* __restrict__ Wr, const float* __restrict__ br,
    const float* __restrict__ Wo, const float* __restrict__ bo,
    float* __restrict__ G, int t0, int chunk)
{
    const int g = blockIdx.x;
    const int tid = threadIdx.x;
    const int rows = B * chunk;
    const int r0 = blockIdx.y * 512 + tid;       // row-set 0
    const int r1 = r0 + 256;                     // row-set 1

    __shared__ float Wlds[64][32];
    __shared__ float blds[64];

    const float* W; const float* bias; int row0;
    if (g < 16)      { W = Wj; bias = bj; row0 = g * H; }
    else if (g < 80) { W = Wr; bias = br; row0 = (g - 16) * H; }
    else             { W = Wo; bias = bo; row0 = 0; }

    {   // cooperative stage: 512 float4 by 256 threads (2 each) + bias
        const int wr = tid >> 2, jj = (tid & 3) * 2;
        const float4* src = (const float4*)(W + (size_t)(row0 + wr) * A);
        float4* dst = (float4*)&Wlds[wr][0];
        dst[jj]     = src[jj];
        dst[jj + 1] = src[jj + 1];
        if (tid < 64) blds[tid] = bias[row0 + tid];
    }

    const bool v0 = r0 < rows, v1 = r1 < rows;
    float xa0[32], xa1[32];
    if (v0) {
        const int b = r0 / chunk, tc = r0 % chunk;
        const float4* src = (const float4*)(x_a + ((size_t)b * T + t0 + tc) * A);
        #pragma unroll
        for (int j = 0; j < 8; ++j) {
            float4 v = src[j];
            xa0[4*j] = v.x; xa0[4*j+1] = v.y; xa0[4*j+2] = v.z; xa0[4*j+3] = v.w;
        }
    }
    if (v1) {
        const int b = r1 / chunk, tc = r1 % chunk;
        const float4* src = (const float4*)(x_a + ((size_t)b * T + t0 + tc) * A);
        #pragma unroll
        for (int j = 0; j < 8; ++j) {
            float4 v = src[j];
            xa1[4*j] = v.x; xa1[4*j+1] = v.y; xa1[4*j+2] = v.z; xa1[4*j+3] = v.w;
        }
    }
    __syncthreads();

    float acc0[64], acc1[64];
    #pragma unroll
    for (int c = 0; c < 64; ++c) {
        const float4* w = (const float4*)&Wlds[c][0];  // wave-uniform -> broadcast
        float s0 = 0.f, s1 = 0.f;
        #pragma unroll
        for (int j = 0; j < 8; ++j) {
            float4 wv = w[j];
            s0 += xa0[4*j] * wv.x + xa0[4*j+1] * wv.y + xa0[4*j+2] * wv.z + xa0[4*j+3] * wv.w;
            s1 += xa1[4*j] * wv.x + xa1[4*j+1] * wv.y + xa1[4*j+2] * wv.z + xa1[4*j+3] * wv.w;
        }
        float bb = blds[c];
        acc0[c] = s0 + bb;
        acc1[c] = s1 + bb;
    }

    if (g < 80) {  // thread-local softmax over 64 cols, both rows
        float mx0 = acc0[0], mx1 = acc1[0];
        #pragma unroll
        for (int c = 1; c < 64; ++c) { mx0 = fmaxf(mx0, acc0[c]); mx1 = fmaxf(mx1, acc1[c]); }
        float s0 = 0.f, s1 = 0.f;
        #pragma unroll
        for (int c = 0; c < 64; ++c) {
            acc0[c] = __expf(acc0[c] - mx0); s0 += acc0[c];
            acc1[c] = __expf(acc1[c] - mx1); s1 += acc1[c];
        }
        float i0 = 1.f / s0, i1 = 1.f / s1;
        #pragma unroll
        for (int c = 0; c < 64; ++c) { acc0[c] *= i0; acc1[c] *= i1; }
    } else {
        #pragma unroll
        for (int c = 0; c < 64; ++c) {
            acc0[c] = 1.f / (1.f + __expf(-acc0[c]));
            acc1[c] = 1.f / (1.f + __expf(-acc1[c]));
        }
    }

    if (v0) {
        float4* outp = (float4*)(G + (size_t)r0 * NCOL + g * H);
        #pragma unroll
        for (int j = 0; j < 16; ++j)
            outp[j] = make_float4(acc0[4*j], acc0[4*j+1], acc0[4*j+2], acc0[4*j+3]);
    }
    if (v1) {
        float4* outp = (float4*)(G + (size_t)r1 * NCOL + g * H);
        #pragma unroll
        for (int j = 0; j < 16; ++j)
            outp[j] = make_float4(acc1[4*j], acc1[4*j+1], acc1[4*j+2], acc1[4*j+3]);
    }
}

// ---------------------------------------------------------------------------
// Scan kernel v2: one block per batch, serial over chunk timesteps.
// Register double-buffer prefetch of next step's G row; raw s_barrier with
// lgkmcnt-only drain so global prefetch loads stay in flight across barriers.
// ---------------------------------------------------------------------------
__global__ __launch_bounds__(256) void scan_kernel(
    const float* __restrict__ G,
    const float* __restrict__ x_m,
    const float* __restrict__ Wfc, const float* __restrict__ bfc,
    float* __restrict__ out, int t0, int chunk, int first)
{
    const int b = blockIdx.x;
    const int tid = threadIdx.x;
    const int q = tid >> 6, k = tid & 63;

    __shared__ float c_sh[64];
    __shared__ float part[4][64];

    float* cbase = out + B;  // c region: cbase[(b*T + t)*H + k]
    if (tid < 64)
        c_sh[tid] = first ? 0.f : cbase[((size_t)b * T + (t0 - 1)) * H + tid];
    asm volatile("s_waitcnt lgkmcnt(0)" ::: "memory");
    __builtin_amdgcn_s_barrier();

    float ja[4], ra[16], oa, xma[4];
    float jb[4], rb[16], ob, xmb[4];

#define ISSUE(tc, JJ, RR, OO, XX)                                              \
    {                                                                          \
        const float* row_ = G + (size_t)(b * chunk + (tc)) * NCOL;             \
        _Pragma("unroll")                                                      \
        for (int i = 0; i < 4; ++i) JJ[i] = row_[(q * 4 + i) * H + k];         \
        _Pragma("unroll")                                                      \
        for (int i = 0; i < 16; ++i) RR[i] = row_[M * H + (q * 16 + i) * H + k]; \
        OO = row_[M * H + H * H + k];                                          \
        _Pragma("unroll")                                                      \
        for (int i = 0; i < 4; ++i)                                            \
            XX[i] = x_m[((size_t)b * T + t0 + (tc)) * M + q * 4 + i];          \
    }

#define STEP(tc, JJ, RR, OO, XX)                                               \
    {                                                                          \
        float p = 0.f;                                                         \
        _Pragma("unroll")                                                      \
        for (int i = 0; i < 4; ++i) p += XX[i] * JJ[i];                        \
        _Pragma("unroll")                                                      \
        for (int i = 0; i < 16; ++i) p += c_sh[q * 16 + i] * RR[i];            \
        part[q][k] = p;                                                        \
        asm volatile("s_waitcnt lgkmcnt(0)" ::: "memory");                     \
        __builtin_amdgcn_s_barrier();                                          \
        if (q == 0) {                                                          \
            float m_new = part[0][k] + part[1][k] + part[2][k] + part[3][k];   \
            float c_new = (1.f - OO) * m_new;                                  \
            cbase[((size_t)b * T + t0 + (tc)) * H + k] = c_new;                \
            c_sh[k] = c_new;                                                   \
            if (t0 + (tc) == T - 1) {                                          \
                float v = OO * m_new * Wfc[k];                                 \
                _Pragma("unroll")                                              \
                for (int off = 32; off > 0; off >>= 1) v += __shfl_down(v, off); \
                if (k == 0) out[b] = v + bfc[0];                               \
            }                                                                  \
        }                                                                      \
        asm volatile("s_waitcnt lgkmcnt(0)" ::: "memory");                     \
        __builtin_amdgcn_s_barrier();                                          \
    }

    ISSUE(0, ja, ra, oa, xma);
    ISSUE(1, jb, rb, ob, xmb);
    for (int tc = 0; tc < chunk; tc += 2) {
        STEP(tc, ja, ra, oa, xma);
        if (tc + 2 < chunk) ISSUE(tc + 2, ja, ra, oa, xma);
        STEP(tc + 1, jb, rb, ob, xmb);
        if (tc + 3 < chunk) ISSUE(tc + 3, jb, rb, ob, xmb);
    }
#undef ISSUE
#undef STEP
}

// ---------------------------------------------------------------------------
extern "C" void kernel_launch(void* const* d_in, const int* in_sizes, int n_in,
                              void* d_out, int out_size, void* d_ws, size_t ws_size,
                              hipStream_t stream) {
    const float* x_m = (const float*)d_in[0];
    const float* x_a = (const float*)d_in[1];
    const float* Wj  = (const float*)d_in[2];
    const float* bj  = (const float*)d_in[3];
    const float* Wr  = (const float*)d_in[4];
    const float* br  = (const float*)d_in[5];
    const float* Wo  = (const float*)d_in[6];
    const float* bo  = (const float*)d_in[7];
    const float* Wfc = (const float*)d_in[8];
    const float* bfc = (const float*)d_in[9];
    float* out = (float*)d_out;
    float* G   = (float*)d_ws;

    // time-chunk sized to the workspace (42.5 MB at chunk=32); keep >=2
    int chunk = 32;
    while (chunk > 2 && (size_t)B * chunk * NCOL * sizeof(float) > ws_size) chunk >>= 1;

    for (int t0 = 0; t0 < T; t0 += chunk) {
        const int rows = B * chunk;
        gate_kernel<<<dim3(NG, (rows + 511) / 512), 256, 0, stream>>>(
            x_a, Wj, bj, Wr, br, Wo, bo, G, t0, chunk);
        scan_kernel<<<64, 256, 0, stream>>>(
            G, x_m, Wfc, bfc, out, t0, chunk, t0 == 0 ? 1 : 0);
    }
}

// Round 3
// 605.483 us; speedup vs baseline: 2.2635x; 1.0585x over previous
//
#include <hip/hip_runtime.h>

// Problem constants (match reference setup_inputs)
constexpr int B = 64, T = 256, M = 16, A = 32, H = 64;
constexpr int NCOL = M * H + H * H + H;  // 1024 + 4096 + 64 = 5184
constexpr int NG = NCOL / H;             // 81 groups of 64 cols

// ---------------------------------------------------------------------------
// Gate kernel v3: lane = output column. Lane l of each wave holds W[row0+l][*]
// in 32 VGPRs; x_a rows staged in LDS, broadcast-read (wave-uniform float4).
// Softmax = full-wave shfl_xor reduce. Store = 1 dword/lane, 256B coalesced.
// Block = 256 thr (4 waves), each wave does 32 rows of one group.
// ---------------------------------------------------------------------------
__global__ __launch_bounds__(256) void gate_kernel(
    const float* __restrict__ x_a,
    const float* __restrict__ Wj, const float* __restrict__ bj,
    const float* __restrict__ Wr, const float* __restrict__ br,
    const float* __restrict__ Wo, const float* __restrict__ bo,
    float* __restrict__ G, int t0, int chunk)
{
    const int g = blockIdx.x;
    const int tile = blockIdx.y;          // 128 rows per block
    const int tid = threadIdx.x;
    const int lane = tid & 63;
    const int wv = tid >> 6;              // wave 0..3
    const int rows = B * chunk;           // multiple of 128 (chunk >= 2)

    __shared__ __align__(16) float xs[128][32];

    const float* W; const float* bias; int row0;
    if (g < 16)      { W = Wj; bias = bj; row0 = g * H; }
    else if (g < 80) { W = Wr; bias = br; row0 = (g - 16) * H; }
    else             { W = Wo; bias = bo; row0 = 0; }

    // per-lane W row (128B), reused for all 128 rows
    float4 w4[8];
    {
        const float4* wp = (const float4*)(W + (size_t)(row0 + lane) * A);
        #pragma unroll
        for (int j = 0; j < 8; ++j) w4[j] = wp[j];
    }
    const float bl = bias[row0 + lane];

    // stage x_a tile: 128 rows x 32 floats (16 KB); 2 threads per row
    {
        const int rl = tid >> 1, j0 = (tid & 1) * 4;
        const int r = tile * 128 + rl;
        const int bb = r / chunk, tc = r % chunk;
        const float4* src = (const float4*)(x_a + ((size_t)bb * T + t0 + tc) * A);
        float4* dst = (float4*)&xs[rl][0];
        #pragma unroll
        for (int j = 0; j < 4; ++j) dst[j0 + j] = src[j0 + j];
    }
    __syncthreads();

    const int rbase = tile * 128 + wv * 32;
    for (int i = 0; i < 32; ++i) {
        const int r = rbase + i;
        const float4* xv = (const float4*)&xs[wv * 32 + i][0];  // wave-uniform
        float s = bl;
        #pragma unroll
        for (int j = 0; j < 8; ++j) {
            float4 x = xv[j];
            s += x.x * w4[j].x + x.y * w4[j].y + x.z * w4[j].z + x.w * w4[j].w;
        }
        float val;
        if (g < 80) {   // softmax across the 64 lanes
            float m = s;
            #pragma unroll
            for (int off = 32; off >= 1; off >>= 1) m = fmaxf(m, __shfl_xor(m, off));
            float e = __expf(s - m);
            float sum = e;
            #pragma unroll
            for (int off = 32; off >= 1; off >>= 1) sum += __shfl_xor(sum, off);
            val = __fdividef(e, sum);
        } else {        // out-gate sigmoid
            val = __fdividef(1.f, 1.f + __expf(-s));
        }
        G[(size_t)r * NCOL + g * H + lane] = val;
    }
}

// ---------------------------------------------------------------------------
// Scan kernel v3: ONE WAVE per batch -> no barriers at all. Lane k owns
// column k. c kept in a 256B LDS array (same-wave ds_write -> broadcast
// ds_read_b128, lgkmcnt-ordered by compiler). R/J/o/x_m register-prefetched
// 2 steps ahead; stores fire-and-forget.
// ---------------------------------------------------------------------------
__global__ __launch_bounds__(64) void scan_kernel(
    const float* __restrict__ G,
    const float* __restrict__ x_m,
    const float* __restrict__ Wfc, const float* __restrict__ bfc,
    float* __restrict__ out, int t0, int chunk, int first)
{
    const int b = blockIdx.x;
    const int k = threadIdx.x;

    __shared__ __align__(16) float c_sh[64];

    float* cbase = out + B;  // c region: cbase[(b*T + t)*H + k]
    c_sh[k] = first ? 0.f : cbase[((size_t)b * T + (t0 - 1)) * H + k];

    float ra[64], ja[16], xma[16], oa;
    float rb[64], jb[16], xmb[16], ob;

#define ISSUE(tc, R_, J_, XM_, O_)                                             \
    {                                                                          \
        const float* row_ = G + (size_t)(b * chunk + (tc)) * NCOL;             \
        _Pragma("unroll")                                                      \
        for (int h = 0; h < 64; ++h) R_[h] = row_[M * H + h * H + k];          \
        _Pragma("unroll")                                                      \
        for (int m = 0; m < 16; ++m) J_[m] = row_[m * H + k];                  \
        O_ = row_[M * H + H * H + k];                                          \
        const float4* xmp = (const float4*)(x_m + ((size_t)b * T + t0 + (tc)) * M); \
        _Pragma("unroll")                                                      \
        for (int q2 = 0; q2 < 4; ++q2) {                                       \
            float4 v = xmp[q2];                                                \
            XM_[4*q2] = v.x; XM_[4*q2+1] = v.y; XM_[4*q2+2] = v.z; XM_[4*q2+3] = v.w; \
        }                                                                      \
    }

#define STEP(tc, R_, J_, XM_, O_)                                              \
    {                                                                          \
        float mi = 0.f;                                                        \
        _Pragma("unroll")                                                      \
        for (int m = 0; m < 16; ++m) mi += XM_[m] * J_[m];                     \
        float p0 = 0.f, p1 = 0.f, p2 = 0.f, p3 = 0.f;                          \
        _Pragma("unroll")                                                      \
        for (int h4 = 0; h4 < 16; ++h4) {                                      \
            const float4 cv = *(const float4*)&c_sh[h4 * 4];                   \
            p0 += cv.x * R_[h4*4+0]; p1 += cv.y * R_[h4*4+1];                  \
            p2 += cv.z * R_[h4*4+2]; p3 += cv.w * R_[h4*4+3];                  \
        }                                                                      \
        float m_new = mi + ((p0 + p1) + (p2 + p3));                            \
        float c_new = (1.f - O_) * m_new;                                      \
        c_sh[k] = c_new;                                                       \
        cbase[((size_t)b * T + t0 + (tc)) * H + k] = c_new;                    \
        if (t0 + (tc) == T - 1) {                                              \
            float v = O_ * m_new * Wfc[k];                                     \
            _Pragma("unroll")                                                  \
            for (int off = 32; off >= 1; off >>= 1) v += __shfl_xor(v, off);   \
            if (k == 0) out[b] = v + bfc[0];                                   \
        }                                                                      \
    }

    ISSUE(0, ra, ja, xma, oa);
    ISSUE(1, rb, jb, xmb, ob);
    for (int tc = 0; tc < chunk; tc += 2) {
        STEP(tc, ra, ja, xma, oa);
        if (tc + 2 < chunk) ISSUE(tc + 2, ra, ja, xma, oa);
        STEP(tc + 1, rb, jb, xmb, ob);
        if (tc + 3 < chunk) ISSUE(tc + 3, rb, jb, xmb, ob);
    }
#undef ISSUE
#undef STEP
}

// ---------------------------------------------------------------------------
extern "C" void kernel_launch(void* const* d_in, const int* in_sizes, int n_in,
                              void* d_out, int out_size, void* d_ws, size_t ws_size,
                              hipStream_t stream) {
    const float* x_m = (const float*)d_in[0];
    const float* x_a = (const float*)d_in[1];
    const float* Wj  = (const float*)d_in[2];
    const float* bj  = (const float*)d_in[3];
    const float* Wr  = (const float*)d_in[4];
    const float* br  = (const float*)d_in[5];
    const float* Wo  = (const float*)d_in[6];
    const float* bo  = (const float*)d_in[7];
    const float* Wfc = (const float*)d_in[8];
    const float* bfc = (const float*)d_in[9];
    float* out = (float*)d_out;
    float* G   = (float*)d_ws;

    // time-chunk: cap at 64 (G stays L3-resident ~85MB), shrink to fit ws
    int chunk = 64;
    while (chunk > 2 && (size_t)B * chunk * NCOL * sizeof(float) > ws_size) chunk >>= 1;

    for (int t0 = 0; t0 < T; t0 += chunk) {
        const int rows = B * chunk;
        gate_kernel<<<dim3(NG, rows / 128), 256, 0, stream>>>(
            x_a, Wj, bj, Wr, br, Wo, bo, G, t0, chunk);
        scan_kernel<<<64, 64, 0, stream>>>(
            G, x_m, Wfc, bfc, out, t0, chunk, t0 == 0 ? 1 : 0);
    }
}

// Round 4
// 453.023 us; speedup vs baseline: 3.0253x; 1.3365x over previous
//
#include <hip/hip_runtime.h>

// Problem constants (match reference setup_inputs)
constexpr int B = 64, T = 256, M = 16, A = 32, H = 64;
constexpr int NCOL = M * H + H * H + H;  // 1024 + 4096 + 64 = 5184
constexpr int NG = NCOL / H;             // 81 groups of 64 cols

// ---------------------------------------------------------------------------
// Gate kernel v4: thread = row. Each thread computes one (b,t)-row x one
// 64-col group entirely in registers (acc[64]); softmax is THREAD-LOCAL
// (no cross-lane ops). W group broadcast from LDS (wave-uniform b128 reads).
// Stores coalesced via per-wave LDS transpose in 16-col chunks (LDS 26KB).
// ---------------------------------------------------------------------------
__global__ __launch_bounds__(256, 2) void gate_kernel(
    const float* __restrict__ x_a,
    const float* __restrict__ Wj, const float* __restrict__ bj,
    const float* __restrict__ Wr, const float* __restrict__ br,
    const float* __restrict__ Wo, const float* __restrict__ bo,
    float* __restrict__ G, int t0, int chunk)
{
    const int g = blockIdx.x;
    const int tid = threadIdx.x;
    const int lane = tid & 63;
    const int wv = tid >> 6;

    __shared__ float4 W4[512];          // 8KB: W[c] row j4 at W4[c*8+j4]
    __shared__ float bs[64];
    __shared__ float tr[4][64][17];     // 17.4KB transpose staging (16 cols + pad)

    const float* Wp; const float* bp; int row0;
    if (g < 16)      { Wp = Wj; bp = bj; row0 = g * H; }
    else if (g < 80) { Wp = Wr; bp = br; row0 = (g - 16) * H; }
    else             { Wp = Wo; bp = bo; row0 = 0; }

    {   // cooperative W stage: 512 float4 by 256 threads (2 each) + bias
        const float4* src = (const float4*)(Wp + (size_t)row0 * A);
        W4[tid * 2]     = src[tid * 2];
        W4[tid * 2 + 1] = src[tid * 2 + 1];
        if (tid < 64) bs[tid] = bp[row0 + tid];
    }

    // this thread's row: per-thread contiguous 128B load (L1 absorbs re-reads)
    const int r0 = blockIdx.y * 256 + tid;
    const int bb = r0 / chunk, tcc = r0 % chunk;
    float4 xa[8];
    {
        const float4* src = (const float4*)(x_a + ((size_t)bb * T + t0 + tcc) * A);
        #pragma unroll
        for (int j = 0; j < 8; ++j) xa[j] = src[j];
    }
    __syncthreads();

    float acc[64];
    #pragma unroll
    for (int c = 0; c < 64; ++c) {
        float s = bs[c];
        #pragma unroll
        for (int j = 0; j < 8; ++j) {
            float4 w = W4[c * 8 + j];   // wave-uniform -> LDS broadcast
            s += xa[j].x * w.x + xa[j].y * w.y + xa[j].z * w.z + xa[j].w * w.w;
        }
        acc[c] = s;
    }

    if (g < 80) {   // thread-local softmax over 64 register values
        float t32[32];
        #pragma unroll
        for (int i = 0; i < 32; ++i) t32[i] = fmaxf(acc[i], acc[i + 32]);
        #pragma unroll
        for (int i = 0; i < 16; ++i) t32[i] = fmaxf(t32[i], t32[i + 16]);
        #pragma unroll
        for (int i = 0; i < 8; ++i)  t32[i] = fmaxf(t32[i], t32[i + 8]);
        #pragma unroll
        for (int i = 0; i < 4; ++i)  t32[i] = fmaxf(t32[i], t32[i + 4]);
        float mx = fmaxf(fmaxf(t32[0], t32[1]), fmaxf(t32[2], t32[3]));
        float s0 = 0.f, s1 = 0.f, s2 = 0.f, s3 = 0.f;
        #pragma unroll
        for (int i = 0; i < 16; ++i) {
            acc[4*i+0] = __expf(acc[4*i+0] - mx); s0 += acc[4*i+0];
            acc[4*i+1] = __expf(acc[4*i+1] - mx); s1 += acc[4*i+1];
            acc[4*i+2] = __expf(acc[4*i+2] - mx); s2 += acc[4*i+2];
            acc[4*i+3] = __expf(acc[4*i+3] - mx); s3 += acc[4*i+3];
        }
        float inv = 1.f / ((s0 + s1) + (s2 + s3));
        #pragma unroll
        for (int c = 0; c < 64; ++c) acc[c] *= inv;
    } else {        // out-gate sigmoid
        #pragma unroll
        for (int c = 0; c < 64; ++c) acc[c] = 1.f / (1.f + __expf(-acc[c]));
    }

    // transpose via per-wave LDS, 16 cols per pass; coalesced 64B stores
    const int sr = lane >> 2, sc = lane & 3;
    const int rowbase = blockIdx.y * 256 + wv * 64;
    #pragma unroll
    for (int cc = 0; cc < 4; ++cc) {
        #pragma unroll
        for (int c4 = 0; c4 < 4; ++c4)
            *(float4*)&tr[wv][lane][c4 * 4] = make_float4(
                acc[cc*16 + c4*4 + 0], acc[cc*16 + c4*4 + 1],
                acc[cc*16 + c4*4 + 2], acc[cc*16 + c4*4 + 3]);
        asm volatile("s_waitcnt lgkmcnt(0)" ::: "memory");
        #pragma unroll
        for (int i = 0; i < 4; ++i) {
            float4 v = *(const float4*)&tr[wv][i * 16 + sr][sc * 4];
            *(float4*)(G + (size_t)(rowbase + i * 16 + sr) * NCOL + g * H + cc * 16 + sc * 4) = v;
        }
        asm volatile("s_waitcnt lgkmcnt(0)" ::: "memory");  // reads done before reuse
    }
}

// ---------------------------------------------------------------------------
// Scan kernel v5: one wave per batch, TRIPLE-buffered register prefetch
// (2 steps ahead; R loads depend only on (b,t), never on c). ~300 VGPR is
// fine: only 64 waves exist on the chip. x_m staged once in LDS.
// ---------------------------------------------------------------------------
__global__ __launch_bounds__(64, 1) void scan_kernel(
    const float* __restrict__ G,
    const float* __restrict__ x_m,
    const float* __restrict__ Wfc, const float* __restrict__ bfc,
    float* __restrict__ out, int t0, int chunk, int first)
{
    const int b = blockIdx.x;
    const int k = threadIdx.x;

    __shared__ __align__(16) float c_sh[64];
    __shared__ __align__(16) float xm_s[64 * M];   // chunk <= 64

    float* cbase = out + B;  // c region: cbase[(b*T + t)*H + k]

    for (int i = k; i < chunk * M; i += 64)
        xm_s[i] = x_m[((size_t)b * T + t0) * M + i];
    c_sh[k] = first ? 0.f : cbase[((size_t)b * T + (t0 - 1)) * H + k];

    float R0[64], R1[64], R2[64];
    float J0[16], J1[16], J2[16];
    float o0, o1, o2;

#define ISSUE(tc_, R_, J_, O_)                                                  \
    if ((tc_) < chunk) {                                                        \
        const float* row_ = G + (size_t)(b * chunk + (tc_)) * NCOL + k;         \
        _Pragma("unroll")                                                       \
        for (int h = 0; h < 64; ++h) R_[h] = row_[M * H + h * H];               \
        _Pragma("unroll")                                                       \
        for (int m = 0; m < 16; ++m) J_[m] = row_[m * H];                       \
        O_ = row_[M * H + H * H];                                               \
    }

#define STEP(tc_, R_, J_, O_)                                                   \
    if ((tc_) < chunk) {                                                        \
        float mi0 = 0.f, mi1 = 0.f, mi2 = 0.f, mi3 = 0.f;                       \
        _Pragma("unroll")                                                       \
        for (int q = 0; q < 4; ++q) {                                           \
            float4 xv = *(const float4*)&xm_s[(tc_) * M + q * 4];               \
            mi0 += xv.x * J_[q*4+0]; mi1 += xv.y * J_[q*4+1];                   \
            mi2 += xv.z * J_[q*4+2]; mi3 += xv.w * J_[q*4+3];                   \
        }                                                                       \
        float p0=0,p1=0,p2=0,p3=0,p4=0,p5=0,p6=0,p7=0;                          \
        _Pragma("unroll")                                                       \
        for (int hq = 0; hq < 4; ++hq) {                                        \
            float4 c0 = *(const float4*)&c_sh[hq*16 + 0];                       \
            float4 c1 = *(const float4*)&c_sh[hq*16 + 4];                       \
            float4 c2 = *(const float4*)&c_sh[hq*16 + 8];                       \
            float4 c3 = *(const float4*)&c_sh[hq*16 + 12];                      \
            p0 += c0.x * R_[hq*16+0];  p1 += c0.y * R_[hq*16+1];                \
            p2 += c0.z * R_[hq*16+2];  p3 += c0.w * R_[hq*16+3];                \
            p4 += c1.x * R_[hq*16+4];  p5 += c1.y * R_[hq*16+5];                \
            p6 += c1.z * R_[hq*16+6];  p7 += c1.w * R_[hq*16+7];                \
            p0 += c2.x * R_[hq*16+8];  p1 += c2.y * R_[hq*16+9];                \
            p2 += c2.z * R_[hq*16+10]; p3 += c2.w * R_[hq*16+11];               \
            p4 += c3.x * R_[hq*16+12]; p5 += c3.y * R_[hq*16+13];               \
            p6 += c3.z * R_[hq*16+14]; p7 += c3.w * R_[hq*16+15];               \
        }                                                                       \
        float m_new = ((mi0+mi1)+(mi2+mi3)) + (((p0+p1)+(p2+p3)) + ((p4+p5)+(p6+p7))); \
        float c_new = (1.f - O_) * m_new;                                       \
        c_sh[k] = c_new;                                                        \
        __builtin_amdgcn_wave_barrier();                                        \
        cbase[((size_t)b * T + t0 + (tc_)) * H + k] = c_new;                    \
        if (t0 + (tc_) == T - 1) {                                              \
            float v = O_ * m_new * Wfc[k];                                      \
            _Pragma("unroll")                                                   \
            for (int off = 32; off >= 1; off >>= 1) v += __shfl_xor(v, off);    \
            if (k == 0) out[b] = v + bfc[0];                                    \
        }                                                                       \
    }

    ISSUE(0, R0, J0, o0);
    ISSUE(1, R1, J1, o1);
    ISSUE(2, R2, J2, o2);
    for (int tc = 0; tc < chunk; tc += 3) {
        STEP(tc,     R0, J0, o0);  ISSUE(tc + 3, R0, J0, o0);
        STEP(tc + 1, R1, J1, o1);  ISSUE(tc + 4, R1, J1, o1);
        STEP(tc + 2, R2, J2, o2);  ISSUE(tc + 5, R2, J2, o2);
    }
#undef ISSUE
#undef STEP
}

// ---------------------------------------------------------------------------
extern "C" void kernel_launch(void* const* d_in, const int* in_sizes, int n_in,
                              void* d_out, int out_size, void* d_ws, size_t ws_size,
                              hipStream_t stream) {
    const float* x_m = (const float*)d_in[0];
    const float* x_a = (const float*)d_in[1];
    const float* Wj  = (const float*)d_in[2];
    const float* bj  = (const float*)d_in[3];
    const float* Wr  = (const float*)d_in[4];
    const float* br  = (const float*)d_in[5];
    const float* Wo  = (const float*)d_in[6];
    const float* bo  = (const float*)d_in[7];
    const float* Wfc = (const float*)d_in[8];
    const float* bfc = (const float*)d_in[9];
    float* out = (float*)d_out;
    float* G   = (float*)d_ws;

    // time-chunk: cap at 64 (G stays L3-resident ~85MB), shrink to fit ws
    int chunk = 64;
    while (chunk > 4 && (size_t)B * chunk * NCOL * sizeof(float) > ws_size) chunk >>= 1;

    for (int t0 = 0; t0 < T; t0 += chunk) {
        const int rows = B * chunk;
        gate_kernel<<<dim3(NG, rows / 256), 256, 0, stream>>>(
            x_a, Wj, bj, Wr, br, Wo, bo, G, t0, chunk);
        scan_kernel<<<64, 64, 0, stream>>>(
            G, x_m, Wfc, bfc, out, t0, chunk, t0 == 0 ? 1 : 0);
    }
}

// Round 5
// 448.674 us; speedup vs baseline: 3.0546x; 1.0097x over previous
//
#include <hip/hip_runtime.h>

// Problem constants (match reference setup_inputs)
constexpr int B = 64, T = 256, M = 16, A = 32, H = 64;
constexpr int NCOL  = M * H + H * H + H;  // 1024 + 4096 + 64 = 5184 used cols
constexpr int NCOLP = 5376;               // padded row stride: 21504 B = 21 x 1KB DMA
constexpr int NG = 81;                    // 16 J + 64 R + 1 o groups of 64 cols

// ---------------------------------------------------------------------------
// Gate kernel v4.5: thread = 2 rows x one 64-col group. acc in registers,
// softmax thread-local, W broadcast from LDS (amortized over 2 rows),
// stores coalesced via per-wave LDS transpose.
// ---------------------------------------------------------------------------
__device__ __forceinline__ void softmax64(float (&acc)[64]) {
    float t32[32];
    #pragma unroll
    for (int i = 0; i < 32; ++i) t32[i] = fmaxf(acc[i], acc[i + 32]);
    #pragma unroll
    for (int i = 0; i < 16; ++i) t32[i] = fmaxf(t32[i], t32[i + 16]);
    #pragma unroll
    for (int i = 0; i < 8; ++i)  t32[i] = fmaxf(t32[i], t32[i + 8]);
    #pragma unroll
    for (int i = 0; i < 4; ++i)  t32[i] = fmaxf(t32[i], t32[i + 4]);
    float mx = fmaxf(fmaxf(t32[0], t32[1]), fmaxf(t32[2], t32[3]));
    float s0 = 0.f, s1 = 0.f, s2 = 0.f, s3 = 0.f;
    #pragma unroll
    for (int i = 0; i < 16; ++i) {
        acc[4*i+0] = __expf(acc[4*i+0] - mx); s0 += acc[4*i+0];
        acc[4*i+1] = __expf(acc[4*i+1] - mx); s1 += acc[4*i+1];
        acc[4*i+2] = __expf(acc[4*i+2] - mx); s2 += acc[4*i+2];
        acc[4*i+3] = __expf(acc[4*i+3] - mx); s3 += acc[4*i+3];
    }
    float inv = 1.f / ((s0 + s1) + (s2 + s3));
    #pragma unroll
    for (int c = 0; c < 64; ++c) acc[c] *= inv;
}

__global__ __launch_bounds__(256, 2) void gate_kernel(
    const float* __restrict__ x_a,
    const float* __restrict__ Wj, const float* __restrict__ bj,
    const float* __restrict__ Wr, const float* __restrict__ br,
    const float* __restrict__ Wo, const float* __restrict__ bo,
    float* __restrict__ G, int t0, int chunk)
{
    const int g = blockIdx.x;
    const int tid = threadIdx.x;
    const int lane = tid & 63;
    const int wv = tid >> 6;

    __shared__ float4 W4[512];          // 8KB
    __shared__ float bs[64];
    __shared__ float tr[4][64][20];     // 20.5KB transpose staging (b128-aligned)

    const float* Wp; const float* bp; int row0;
    if (g < 16)      { Wp = Wj; bp = bj; row0 = g * H; }
    else if (g < 80) { Wp = Wr; bp = br; row0 = (g - 16) * H; }
    else             { Wp = Wo; bp = bo; row0 = 0; }

    {   // cooperative W stage + bias
        const float4* src = (const float4*)(Wp + (size_t)row0 * A);
        W4[tid * 2]     = src[tid * 2];
        W4[tid * 2 + 1] = src[tid * 2 + 1];
        if (tid < 64) bs[tid] = bp[row0 + tid];
    }

    const int r0 = blockIdx.y * 512 + tid;   // rows always multiple of 512
    const int r1 = r0 + 256;
    float4 xa0[8], xa1[8];
    {
        const int b0 = r0 / chunk, tc0 = r0 % chunk;
        const float4* s0 = (const float4*)(x_a + ((size_t)b0 * T + t0 + tc0) * A);
        #pragma unroll
        for (int j = 0; j < 8; ++j) xa0[j] = s0[j];
        const int b1 = r1 / chunk, tc1 = r1 % chunk;
        const float4* s1 = (const float4*)(x_a + ((size_t)b1 * T + t0 + tc1) * A);
        #pragma unroll
        for (int j = 0; j < 8; ++j) xa1[j] = s1[j];
    }
    __syncthreads();

    float acc0[64], acc1[64];
    #pragma unroll
    for (int c = 0; c < 64; ++c) {
        float s0 = bs[c], s1 = bs[c];
        #pragma unroll
        for (int j = 0; j < 8; ++j) {
            float4 w = W4[c * 8 + j];   // wave-uniform -> LDS broadcast
            s0 += xa0[j].x * w.x + xa0[j].y * w.y + xa0[j].z * w.z + xa0[j].w * w.w;
            s1 += xa1[j].x * w.x + xa1[j].y * w.y + xa1[j].z * w.z + xa1[j].w * w.w;
        }
        acc0[c] = s0; acc1[c] = s1;
    }

    if (g < 80) { softmax64(acc0); softmax64(acc1); }
    else {
        #pragma unroll
        for (int c = 0; c < 64; ++c) {
            acc0[c] = 1.f / (1.f + __expf(-acc0[c]));
            acc1[c] = 1.f / (1.f + __expf(-acc1[c]));
        }
    }

    // transpose via per-wave LDS (in-order DS pipe), coalesced 64B stores
    const int sr = lane >> 2, sc = lane & 3;
#define STORE_SET(ACC, RB)                                                      \
    {                                                                           \
        _Pragma("unroll")                                                       \
        for (int cc = 0; cc < 4; ++cc) {                                        \
            _Pragma("unroll")                                                   \
            for (int c4 = 0; c4 < 4; ++c4)                                      \
                *(float4*)&tr[wv][lane][c4 * 4] = make_float4(                  \
                    ACC[cc*16 + c4*4 + 0], ACC[cc*16 + c4*4 + 1],               \
                    ACC[cc*16 + c4*4 + 2], ACC[cc*16 + c4*4 + 3]);              \
            asm volatile("s_waitcnt lgkmcnt(0)" ::: "memory");                  \
            _Pragma("unroll")                                                   \
            for (int i = 0; i < 4; ++i) {                                       \
                float4 v = *(const float4*)&tr[wv][i * 16 + sr][sc * 4];        \
                *(float4*)(G + (size_t)((RB) + i * 16 + sr) * NCOLP             \
                             + g * H + cc * 16 + sc * 4) = v;                   \
            }                                                                   \
            asm volatile("s_waitcnt lgkmcnt(0)" ::: "memory");                  \
        }                                                                       \
    }
    const int rb0 = blockIdx.y * 512 + wv * 64;
    STORE_SET(acc0, rb0);
    STORE_SET(acc1, rb0 + 256);
#undef STORE_SET
}

// ---------------------------------------------------------------------------
// Scan kernel v7: one wave per batch. G-row async-DMA'd to LDS
// (global_load_lds dwordx4, triple-buffered, counted vmcnt -- never 0
// mid-loop). Lane l = (k-quad q=l&15, h-range hr=l>>4); b128 LDS reads;
// in-wave shfl_xor reduce. No barriers, no register pressure.
// ---------------------------------------------------------------------------
__global__ __launch_bounds__(64, 1) void scan_kernel(
    const float* __restrict__ G,
    const float* __restrict__ x_m,
    const float* __restrict__ Wfc, const float* __restrict__ bfc,
    float* __restrict__ out, int t0, int chunk, int first)
{
    const int b = blockIdx.x;
    const int l = threadIdx.x;
    const int q = l & 15;    // k-quad: k = 4q..4q+3
    const int hr = l >> 4;   // h-range: h = hr*16 .. hr*16+15

    __shared__ __align__(16) float buf[3][NCOLP];   // 63KB triple buffer
    __shared__ __align__(16) float c_sh[64];
    __shared__ __align__(16) float xm_s[1024];      // chunk<=64

    float* cbase = out + B;  // c region: cbase[(b*T + t)*H + k]

    {   // stage x_m chunk (chunk*16 floats)
        const float4* src = (const float4*)(x_m + ((size_t)b * T + t0) * M);
        float4* dst = (float4*)xm_s;
        for (int i = l; i < chunk * 4; i += 64) dst[i] = src[i];
    }
    c_sh[l] = first ? 0.f : cbase[((size_t)b * T + (t0 - 1)) * H + l];
    const float4 wfc4 = *(const float4*)&Wfc[q * 4];
    const float bfc0 = bfc[0];
    asm volatile("s_waitcnt vmcnt(0) lgkmcnt(0)" ::: "memory");

#define DMA(tc_)                                                                \
    {                                                                           \
        const float* rp_ = G + (size_t)(b * chunk + (tc_)) * NCOLP;             \
        float* lb_ = &buf[(tc_) % 3][0];                                        \
        _Pragma("unroll")                                                       \
        for (int i_ = 0; i_ < 21; ++i_)                                         \
            __builtin_amdgcn_global_load_lds(                                   \
                (const __attribute__((address_space(1))) unsigned int*)         \
                    (rp_ + i_ * 256 + l * 4),                                   \
                (__attribute__((address_space(3))) unsigned int*)               \
                    (lb_ + i_ * 256), 16, 0, 0);                                \
    }

    DMA(0); DMA(1); DMA(2);

    for (int tc = 0; tc < chunk; ++tc) {
        // conservative counted waits: N = min #VMEM-ops issued after DMA(tc)
        if (tc + 3 <= chunk)      asm volatile("s_waitcnt vmcnt(42)" ::: "memory");
        else if (tc + 2 == chunk) asm volatile("s_waitcnt vmcnt(21)" ::: "memory");
        else                      asm volatile("s_waitcnt vmcnt(0)"  ::: "memory");
        __builtin_amdgcn_sched_barrier(0);

        const float* bp2 = &buf[tc % 3][0];

        float cc[16];
        #pragma unroll
        for (int i = 0; i < 16; ++i) cc[i] = c_sh[hr * 16 + i];
        float xm[4];
        #pragma unroll
        for (int j = 0; j < 4; ++j) xm[j] = xm_s[tc * 16 + hr * 4 + j];

        float a0 = 0.f, a1 = 0.f, a2 = 0.f, a3 = 0.f;
        #pragma unroll
        for (int j = 0; j < 4; ++j) {
            const float4 jv = *(const float4*)&bp2[(hr * 4 + j) * 64 + q * 4];
            a0 += xm[j] * jv.x; a1 += xm[j] * jv.y;
            a2 += xm[j] * jv.z; a3 += xm[j] * jv.w;
        }
        #pragma unroll
        for (int i = 0; i < 16; ++i) {
            const float4 rv = *(const float4*)&bp2[1024 + (hr * 16 + i) * 64 + q * 4];
            a0 += cc[i] * rv.x; a1 += cc[i] * rv.y;
            a2 += cc[i] * rv.z; a3 += cc[i] * rv.w;
        }
        const float4 o4 = *(const float4*)&bp2[5120 + q * 4];

        // reduce partials across the 4 h-ranges (lanes ^16, ^32)
        a0 += __shfl_xor(a0, 16); a1 += __shfl_xor(a1, 16);
        a2 += __shfl_xor(a2, 16); a3 += __shfl_xor(a3, 16);
        a0 += __shfl_xor(a0, 32); a1 += __shfl_xor(a1, 32);
        a2 += __shfl_xor(a2, 32); a3 += __shfl_xor(a3, 32);

        const float cn0 = (1.f - o4.x) * a0;
        const float cn1 = (1.f - o4.y) * a1;
        const float cn2 = (1.f - o4.z) * a2;
        const float cn3 = (1.f - o4.w) * a3;

        if (hr == 0) {   // 16 lanes: write c_sh + coalesced 256B global store
            *(float4*)&c_sh[q * 4] = make_float4(cn0, cn1, cn2, cn3);
            *(float4*)(cbase + ((size_t)b * T + t0 + tc) * H + q * 4) =
                make_float4(cn0, cn1, cn2, cn3);
        }
        if (t0 + tc == T - 1) {  // fused fc on last timestep
            float v = o4.x * a0 * wfc4.x + o4.y * a1 * wfc4.y +
                      o4.z * a2 * wfc4.z + o4.w * a3 * wfc4.w;
            v += __shfl_xor(v, 1); v += __shfl_xor(v, 2);
            v += __shfl_xor(v, 4); v += __shfl_xor(v, 8);
            if (l == 0) out[b] = v + bfc0;
        }

        if (tc + 3 < chunk) {
            asm volatile("s_waitcnt lgkmcnt(0)" ::: "memory");  // LDS reads done
            DMA(tc + 3);
        }
    }
#undef DMA
}

// ---------------------------------------------------------------------------
extern "C" void kernel_launch(void* const* d_in, const int* in_sizes, int n_in,
                              void* d_out, int out_size, void* d_ws, size_t ws_size,
                              hipStream_t stream) {
    const float* x_m = (const float*)d_in[0];
    const float* x_a = (const float*)d_in[1];
    const float* Wj  = (const float*)d_in[2];
    const float* bj  = (const float*)d_in[3];
    const float* Wr  = (const float*)d_in[4];
    const float* br  = (const float*)d_in[5];
    const float* Wo  = (const float*)d_in[6];
    const float* bo  = (const float*)d_in[7];
    const float* Wfc = (const float*)d_in[8];
    const float* bfc = (const float*)d_in[9];
    float* out = (float*)d_out;
    float* G   = (float*)d_ws;

    // time-chunk: prefer 64 (88MB G), shrink to fit ws; keep >= 8
    int chunk = 64;
    while (chunk > 8 && (size_t)B * chunk * NCOLP * sizeof(float) > ws_size) chunk >>= 1;

    for (int t0 = 0; t0 < T; t0 += chunk) {
        gate_kernel<<<dim3(NG, (B * chunk) / 512), 256, 0, stream>>>(
            x_a, Wj, bj, Wr, br, Wo, bo, G, t0, chunk);
        scan_kernel<<<64, 64, 0, stream>>>(
            G, x_m, Wfc, bfc, out, t0, chunk, t0 == 0 ? 1 : 0);
    }
}